// Round 1
// baseline (125.337 us; speedup 1.0000x reference)
//
#include <hip/hip_runtime.h>

#define VOCAB 100000
#define EMB   128
#define BATCH 16384
#define NEGS  10

// 4 waves (4 batch elements) per 256-thread block
#define WAVES_PER_BLOCK 4
#define NBLOCKS (BATCH / WAVES_PER_BLOCK)   // 4096, exact

__device__ __forceinline__ float log_sigmoid(float x) {
    // stable: min(x,0) - log1p(exp(-|x|))
    return fminf(x, 0.0f) - log1pf(expf(-fabsf(x)));
}

__global__ __launch_bounds__(256) void w2v_fwd(
    const float* __restrict__ iemb_w,
    const float* __restrict__ oemb_w,
    const int*   __restrict__ iwords,
    const int*   __restrict__ owords,
    const int*   __restrict__ negwords,
    float*       __restrict__ partial)
{
    const int lane = threadIdx.x & 63;
    const int wid  = threadIdx.x >> 6;                  // 0..3
    const int b    = blockIdx.x * WAVES_PER_BLOCK + wid;

    // Each lane owns 2 consecutive floats of the 128-float row.
    const float2* irow = (const float2*)(iemb_w + (size_t)iwords[b] * EMB);
    const float2* orow = (const float2*)(oemb_w + (size_t)owords[b] * EMB);
    float2 iv = irow[lane];
    float2 ov = orow[lane];
    float pos_p = iv.x * ov.x + iv.y * ov.y;

    // Sum the 10 negative rows elementwise, then one dot with iemb.
    float2 nsum = make_float2(0.f, 0.f);
    #pragma unroll
    for (int k = 0; k < NEGS; ++k) {
        const float2* nrow =
            (const float2*)(oemb_w + (size_t)negwords[b * NEGS + k] * EMB);
        float2 nv = nrow[lane];
        nsum.x += nv.x;
        nsum.y += nv.y;
    }
    float neg_p = iv.x * nsum.x + iv.y * nsum.y;

    // Wave reduce both dots (6 butterfly steps over 64 lanes).
    #pragma unroll
    for (int s = 32; s; s >>= 1) {
        pos_p += __shfl_xor(pos_p, s);
        neg_p += __shfl_xor(neg_p, s);
    }

    float val = 0.f;
    if (lane == 0)
        val = -(log_sigmoid(pos_p) + log_sigmoid(-neg_p));

    // Block reduce the 4 wave-leader values.
    __shared__ float sm[WAVES_PER_BLOCK];
    if (lane == 0) sm[wid] = val;
    __syncthreads();
    if (threadIdx.x == 0)
        partial[blockIdx.x] = sm[0] + sm[1] + sm[2] + sm[3];
}

__global__ __launch_bounds__(1024) void w2v_reduce(
    const float* __restrict__ partial, float* __restrict__ out)
{
    float v = 0.f;
    for (int i = threadIdx.x; i < NBLOCKS; i += 1024) v += partial[i];
    #pragma unroll
    for (int s = 32; s; s >>= 1) v += __shfl_xor(v, s);
    __shared__ float sm[16];
    const int lane = threadIdx.x & 63, wid = threadIdx.x >> 6;
    if (lane == 0) sm[wid] = v;
    __syncthreads();
    if (threadIdx.x == 0) {
        float t = 0.f;
        #pragma unroll
        for (int i = 0; i < 16; ++i) t += sm[i];
        *out = t;
    }
}

extern "C" void kernel_launch(void* const* d_in, const int* in_sizes, int n_in,
                              void* d_out, int out_size, void* d_ws, size_t ws_size,
                              hipStream_t stream) {
    const float* iemb_w   = (const float*)d_in[0];
    const float* oemb_w   = (const float*)d_in[1];
    const int*   iwords   = (const int*)d_in[2];
    const int*   owords   = (const int*)d_in[3];
    const int*   negwords = (const int*)d_in[4];
    float* out     = (float*)d_out;
    float* partial = (float*)d_ws;   // NBLOCKS floats = 16 KiB

    w2v_fwd<<<NBLOCKS, 256, 0, stream>>>(iemb_w, oemb_w, iwords, owords,
                                         negwords, partial);
    w2v_reduce<<<1, 1024, 0, stream>>>(partial, out);
}